// Round 1
// baseline (869.184 us; speedup 1.0000x reference)
//
#include <hip/hip_runtime.h>

typedef __attribute__((ext_vector_type(8))) short short8;
typedef __attribute__((ext_vector_type(4))) float floatx4;

__device__ __forceinline__ unsigned short f2bf(float x) {
  union { float f; unsigned u; } v; v.f = x;
  unsigned r = v.u + 0x7fffu + ((v.u >> 16) & 1u);
  return (unsigned short)(r >> 16);
}
__device__ __forceinline__ float sigm_f(float x) { return __fdividef(1.f, 1.f + __expf(-x)); }
__device__ __forceinline__ float tanh_f(float x) {
  float ax = fabsf(x);
  float e = __expf(-2.f * ax);
  float t = 1.f - 2.f * __fdividef(e, 1.f + e);
  return copysignf(t, x);
}
__device__ __forceinline__ floatx4 splat4(float v) { floatx4 r; r[0]=v; r[1]=v; r[2]=v; r[3]=v; return r; }

#define N_WHH  (768*256)
#define N_WCAT (1024*256)
#define N_W1H  (256*256)
#define N_W2   (16*256)
#define N_TOT  (N_WHH + N_WCAT + N_W1H + N_W2)

// Convert weights to bf16 staging buffers.
// Whh : (768,256)   = gru_w_hh
// Wcat: (1024,256)  rows 0-767 = gru_w_ih[:,1:209] (k<208, else 0); rows 768-1023 = w1[:,256:464]
// W1h : (256,256)   = w1[:,0:256]
// W2b : (16,256)    rows 0-8 = w2, rows 9-15 = 0
__global__ void prep_kernel(const float* __restrict__ w_hh, const float* __restrict__ w_ih,
                            const float* __restrict__ w1,  const float* __restrict__ w2,
                            unsigned short* __restrict__ Whh, unsigned short* __restrict__ Wcat,
                            unsigned short* __restrict__ W1h, unsigned short* __restrict__ W2b) {
  int i = blockIdx.x * blockDim.x + threadIdx.x;
  if (i < N_WHH) {
    Whh[i] = f2bf(w_hh[i]);
  } else if (i < N_WHH + N_WCAT) {
    int j = i - N_WHH; int n = j >> 8, k = j & 255;
    float v = 0.f;
    if (k < 208) v = (n < 768) ? w_ih[n * 209 + 1 + k] : w1[(n - 768) * 464 + 256 + k];
    Wcat[j] = f2bf(v);
  } else if (i < N_WHH + N_WCAT + N_W1H) {
    int j = i - N_WHH - N_WCAT; int n = j >> 8, k = j & 255;
    W1h[j] = f2bf(w1[n * 464 + k]);
  } else if (i < N_TOT) {
    int j = i - N_WHH - N_WCAT - N_W1H; int n = j >> 8, k = j & 255;
    W2b[j] = (n < 9) ? f2bf(w2[n * 256 + k]) : (unsigned short)0;
  }
}

// LDS layout (bytes)
#define H_BASE 0        // 4 slots x (16 rows x 512B) bf16 h history, XOR-swizzled
#define U_BASE 32768    // 4 slots x 8KB: u (tanh hidden); slot 0 doubles as cbm tile in prologue
#define P_BASE 65536    // p scratch: 4 x 16 x 17 floats (4352B); also final reduction
#define LDS_SZ 69888

__launch_bounds__(512, 2)
__global__ void fused_kernel(const float* __restrict__ z,  const float* __restrict__ cc,
                             const float* __restrict__ bb, const float* __restrict__ mmat,
                             const float* __restrict__ w_ih, const float* __restrict__ b_ih,
                             const float* __restrict__ b_hh, const float* __restrict__ b1,
                             const float* __restrict__ b2,
                             const unsigned short* __restrict__ Whh,
                             const unsigned short* __restrict__ Wcat,
                             const unsigned short* __restrict__ W1h,
                             const unsigned short* __restrict__ W2b,
                             float* __restrict__ out) {
  __shared__ __align__(16) char smem[LDS_SZ];
  const int tid = threadIdx.x;
  const int w  = tid >> 6;    // wave 0..7, owns gate-cols [w*32, w*32+32)
  const int l  = tid & 63;
  const int q  = l >> 4;      // k-group / row-group
  const int li = l & 15;
  const int r0 = blockIdx.x << 4;   // 16 batch rows per block
  const int sw_a = (li & 7) << 4;   // XOR swizzle for A-frag reads (row = li)

  // zero h_hist slot 3 (= h at t=-1)
  *(floatx4*)(smem + H_BASE + 3 * 8192 + tid * 16) = splat4(0.f);

  // stage cbm = [c(80) | b(64) | m(64) | 0...] as bf16 into U_BASE, swizzled
  {
    int row = tid >> 5, ch = tid & 31;   // ch = 8-col chunk
    float v[8];
#pragma unroll
    for (int j = 0; j < 8; j++) v[j] = 0.f;
    if (ch < 10) {
      const float* s = cc + (r0 + row) * 80 + ch * 8;
#pragma unroll
      for (int j = 0; j < 8; j++) v[j] = s[j];
    } else if (ch < 18) {
      const float* s = bb + (r0 + row) * 64 + (ch - 10) * 8;
#pragma unroll
      for (int j = 0; j < 8; j++) v[j] = s[j];
    } else if (ch < 26) {
      const float* s = mmat + (r0 + row) * 64 + (ch - 18) * 8;
#pragma unroll
      for (int j = 0; j < 8; j++) v[j] = s[j];
    }
    short8 pk;
#pragma unroll
    for (int j = 0; j < 8; j++) pk[j] = (short)f2bf(v[j]);
    *(short8*)(smem + U_BASE + row * 512 + ((ch * 16) ^ ((row & 7) << 4))) = pk;
  }
  __syncthreads();

  // tile -> gate-column map: tiles 0-5 = (gate g = tt>>1, nc = tt&1); tiles 6,7 = const1 (hid)
  int ncol[8];
#pragma unroll
  for (int tt = 0; tt < 8; tt++) {
    if (tt < 6) ncol[tt] = (tt >> 1) * 256 + (w << 5) + ((tt & 1) << 4) + li;
    else        ncol[tt] = 768 + (w << 5) + ((tt & 1) << 4) + li;
  }

  // const GEMM: cst[0..5] = const_ih slices (incl b_ih), cst[6..7] = cbm@W1c^T + b1
  floatx4 cst[8];
#pragma unroll
  for (int tt = 0; tt < 8; tt++) {
    float bv = (tt < 6) ? b_ih[ncol[tt]] : b1[ncol[tt] - 768];
    cst[tt] = splat4(bv);
  }
#pragma unroll
  for (int kk = 0; kk < 7; kk++) {   // K = 224 (zero padded)
    short8 a = *(const short8*)(smem + U_BASE + li * 512 + (((kk << 6) + (q << 4)) ^ sw_a));
#pragma unroll
    for (int tt = 0; tt < 8; tt++) {
      short8 bf = *(const short8*)(Wcat + ncol[tt] * 256 + (kk << 5) + (q << 3));
      cst[tt] = __builtin_amdgcn_mfma_f32_16x16x32_bf16(a, bf, cst[tt], 0, 0, 0);
    }
  }

  // preloads
  float wz[6], bhhv[6];
#pragma unroll
  for (int u6 = 0; u6 < 6; u6++) { wz[u6] = w_ih[ncol[u6] * 209]; bhhv[u6] = b_hh[ncol[u6]]; }
  float b2r[9];
#pragma unroll
  for (int j = 0; j < 9; j++) b2r[j] = b2[j];

  float cntf = 0.f;
  if (w < 4 && l < 16) {
    const float* bp = bb + (r0 + l) * 64;
    const float* mp = mmat + (r0 + l) * 64;
#pragma unroll 8
    for (int k2 = 0; k2 < 64; k2++) cntf += mp[k2] * (1.f - bp[k2]);
  }

  const unsigned short* wrow[6];
#pragma unroll
  for (int u6 = 0; u6 < 6; u6++) wrow[u6] = Whh + ncol[u6] * 256 + (q << 3);
  const unsigned short* w1row[2];
#pragma unroll
  for (int nc = 0; nc < 2; nc++) w1row[nc] = W1h + (ncol[6 + nc] - 768) * 256 + (q << 3);
  const unsigned short* w2row = W2b + li * 256 + (q << 3);

  float hreg[8];
#pragma unroll
  for (int j = 0; j < 8; j++) hreg[j] = 0.f;
  float out_acc = 0.f;
  const int rowz = r0 + (q << 2);

#pragma unroll 1
  for (int t = 0; t < 64; t++) {
    // z_prev for this step (rows rowz..rowz+3)
    float zp[4];
    int tz = (t == 0) ? 0 : (t - 1);
#pragma unroll
    for (int r = 0; r < 4; r++) {
      float zl = z[(rowz + r) * 64 + tz];
      zp[r] = (t == 0) ? -1.f : zl;
    }

    // GRU GEMM: gh = h_prev @ Whh^T + b_hh  (wave's 6 tiles)
    floatx4 acc[6];
#pragma unroll
    for (int u6 = 0; u6 < 6; u6++) acc[u6] = splat4(bhhv[u6]);
    const char* hprev = smem + H_BASE + ((t + 3) & 3) * 8192;
#pragma unroll
    for (int kk = 0; kk < 8; kk++) {
      short8 a = *(const short8*)(hprev + li * 512 + (((kk << 6) + (q << 4)) ^ sw_a));
#pragma unroll
      for (int u6 = 0; u6 < 6; u6++) {
        short8 bf = *(const short8*)(wrow[u6] + (kk << 5));
        acc[u6] = __builtin_amdgcn_mfma_f32_16x16x32_bf16(a, bf, acc[u6], 0, 0, 0);
      }
    }

    // gates + h update (in-register; lane owns (row=q*4+r, col=w*32+nc*16+li))
#pragma unroll
    for (int nc = 0; nc < 2; nc++) {
#pragma unroll
      for (int r = 0; r < 4; r++) {
        float gi_r = fmaf(zp[r], wz[nc],     cst[nc][r]);
        float gi_z = fmaf(zp[r], wz[2 + nc], cst[2 + nc][r]);
        float gi_n = fmaf(zp[r], wz[4 + nc], cst[4 + nc][r]);
        float rr = sigm_f(gi_r + acc[nc][r]);
        float zg = sigm_f(gi_z + acc[2 + nc][r]);
        float nn = tanh_f(fmaf(rr, acc[4 + nc][r], gi_n));
        float hv = fmaf(zg, hreg[nc * 4 + r] - nn, nn);
        hreg[nc * 4 + r] = hv;
      }
    }

    __syncthreads();   // all reads of h_prev done
    {
      char* hcur = smem + H_BASE + (t & 3) * 8192;
#pragma unroll
      for (int nc = 0; nc < 2; nc++) {
#pragma unroll
        for (int r = 0; r < 4; r++) {
          int rw = (q << 2) + r;
          int colb2 = ((w << 5) + (nc << 4) + li) << 1;
          *(unsigned short*)(hcur + rw * 512 + (colb2 ^ ((rw & 7) << 4))) = f2bf(hreg[nc * 4 + r]);
        }
      }
    }
    __syncthreads();   // h_cur visible

    if ((t & 3) == 3) {
      // ---- MLP over the last 4 timesteps (h_hist slots 0..3 = t-3..t) ----
      floatx4 ua[8];   // [tc*2+nc]
#pragma unroll
      for (int j = 0; j < 8; j++) ua[j] = splat4(0.f);
#pragma unroll
      for (int kk = 0; kk < 8; kk++) {
        short8 at[4];
#pragma unroll
        for (int tc = 0; tc < 4; tc++)
          at[tc] = *(const short8*)(smem + H_BASE + tc * 8192 + li * 512 + (((kk << 6) + (q << 4)) ^ sw_a));
#pragma unroll
        for (int nc = 0; nc < 2; nc++) {
          short8 bw = *(const short8*)(w1row[nc] + (kk << 5));
#pragma unroll
          for (int tc = 0; tc < 4; tc++)
            ua[tc * 2 + nc] = __builtin_amdgcn_mfma_f32_16x16x32_bf16(at[tc], bw, ua[tc * 2 + nc], 0, 0, 0);
        }
      }
      // u = tanh(. + const1) -> U_lds (bf16, swizzled)
#pragma unroll
      for (int tc = 0; tc < 4; tc++) {
#pragma unroll
        for (int nc = 0; nc < 2; nc++) {
#pragma unroll
          for (int r = 0; r < 4; r++) {
            float uv = tanh_f(ua[tc * 2 + nc][r] + cst[6 + nc][r]);
            int rw = (q << 2) + r;
            int colb2 = ((w << 5) + (nc << 4) + li) << 1;
            *(unsigned short*)(smem + U_BASE + tc * 8192 + rw * 512 + (colb2 ^ ((rw & 7) << 4))) = f2bf(uv);
          }
        }
      }
      __syncthreads();

      // p = u @ w2^T (waves 0-3, tc = w); C col = j (9 valid), row = batch row
      if (w < 4) {
        floatx4 pacc = splat4(0.f);
#pragma unroll
        for (int kk = 0; kk < 8; kk++) {
          short8 au = *(const short8*)(smem + U_BASE + w * 8192 + li * 512 + (((kk << 6) + (q << 4)) ^ sw_a));
          short8 bw2 = *(const short8*)(w2row + (kk << 5));
          pacc = __builtin_amdgcn_mfma_f32_16x16x32_bf16(au, bw2, pacc, 0, 0, 0);
        }
        float* pl = (float*)(smem + P_BASE);
#pragma unroll
        for (int r = 0; r < 4; r++) pl[w * 272 + ((q << 2) + r) * 17 + li] = pacc[r];
      }
      __syncthreads();

      // GMM log-likelihood epilogue: waves 0-3 lanes 0-15, one row each, t_abs = t-3+w
      if (w < 4 && l < 16) {
        const float* pl = (float*)(smem + P_BASE) + w * 272 + l * 17;
        int ta = t - 3 + w;
        float zt = z[(r0 + l) * 64 + ta];
        float aj[3], lg[3];
#pragma unroll
        for (int j = 0; j < 3; j++) {
          float lgt  = pl[j]     + b2r[j];
          float mean = pl[3 + j] + b2r[3 + j];
          float ls   = pl[6 + j] + b2r[6 + j];
          float d = (zt - mean) * __expf(-ls);
          lg[j] = lgt;
          aj[j] = lgt - ls - 0.9189385332f - 0.5f * d * d;
        }
        float mx = fmaxf(aj[0], fmaxf(aj[1], aj[2]));
        float ln_n = mx + __logf(__expf(aj[0] - mx) + __expf(aj[1] - mx) + __expf(aj[2] - mx));
        float mg = fmaxf(lg[0], fmaxf(lg[1], lg[2]));
        float ln_d = mg + __logf(__expf(lg[0] - mg) + __expf(lg[1] - mg) + __expf(lg[2] - mg));
        if ((float)ta + 0.5f < cntf) out_acc += (ln_n - ln_d);
      }
    }
  }

  // combine the 4 epilogue waves' partial sums
  __syncthreads();
  {
    float* pl = (float*)(smem + P_BASE);
    if (w < 4 && l < 16) pl[w * 16 + l] = out_acc;
  }
  __syncthreads();
  if (w == 0 && l < 16) {
    float* pl = (float*)(smem + P_BASE);
    out[r0 + l] = pl[l] + pl[16 + l] + pl[32 + l] + pl[48 + l];
  }
}

extern "C" void kernel_launch(void* const* d_in, const int* in_sizes, int n_in,
                              void* d_out, int out_size, void* d_ws, size_t ws_size,
                              hipStream_t stream) {
  const float* z    = (const float*)d_in[0];
  const float* c    = (const float*)d_in[1];
  const float* b    = (const float*)d_in[2];
  const float* m    = (const float*)d_in[3];
  const float* w_ih = (const float*)d_in[4];
  const float* w_hh = (const float*)d_in[5];
  const float* b_ih = (const float*)d_in[6];
  const float* b_hh = (const float*)d_in[7];
  const float* w1   = (const float*)d_in[8];
  const float* b1   = (const float*)d_in[9];
  const float* w2   = (const float*)d_in[10];
  const float* b2   = (const float*)d_in[11];

  char* ws = (char*)d_ws;
  unsigned short* Whh  = (unsigned short*)(ws);
  unsigned short* Wcat = (unsigned short*)(ws + 393216);
  unsigned short* W1h  = (unsigned short*)(ws + 917504);
  unsigned short* W2b  = (unsigned short*)(ws + 1048576);

  hipLaunchKernelGGL(prep_kernel, dim3(N_TOT / 256), dim3(256), 0, stream,
                     w_hh, w_ih, w1, w2, Whh, Wcat, W1h, W2b);
  hipLaunchKernelGGL(fused_kernel, dim3(256), dim3(512), 0, stream,
                     z, c, b, m, w_ih, b_ih, b_hh, b1, b2, Whh, Wcat, W1h, W2b,
                     (float*)d_out);
}

// Round 2
// 369.536 us; speedup vs baseline: 2.3521x; 2.3521x over previous
//
#include <hip/hip_runtime.h>

typedef __attribute__((ext_vector_type(8))) short short8;
typedef __attribute__((ext_vector_type(4))) float floatx4;

__device__ __forceinline__ unsigned short f2bf(float x) {
  union { float f; unsigned u; } v; v.f = x;
  unsigned r = v.u + 0x7fffu + ((v.u >> 16) & 1u);
  return (unsigned short)(r >> 16);
}
__device__ __forceinline__ float sigm_f(float x) { return __fdividef(1.f, 1.f + __expf(-x)); }
__device__ __forceinline__ float tanh_f(float x) {
  float ax = fabsf(x);
  float e = __expf(-2.f * ax);
  float t = 1.f - 2.f * __fdividef(e, 1.f + e);
  return copysignf(t, x);
}
__device__ __forceinline__ floatx4 splat4(float v) { floatx4 r; r[0]=v; r[1]=v; r[2]=v; r[3]=v; return r; }

#define N_WHH  (768*256)
#define N_WCAT (1024*256)
#define N_W1H  (256*256)
#define N_W2   (16*256)
#define N_TOT  (N_WHH + N_WCAT + N_W1H + N_W2)

// A-frag / B-frag swizzled byte offset within a 512B row
#define A_SW(kk,q,i) ((((kk)<<6)+((q)<<4)) ^ (((i)&7)<<4))

__global__ void prep_kernel(const float* __restrict__ w_hh, const float* __restrict__ w_ih,
                            const float* __restrict__ w1,  const float* __restrict__ w2,
                            unsigned short* __restrict__ Whh, unsigned short* __restrict__ Wcat,
                            unsigned short* __restrict__ W1h, unsigned short* __restrict__ W2b) {
  int i = blockIdx.x * blockDim.x + threadIdx.x;
  if (i < N_WHH) {
    Whh[i] = f2bf(w_hh[i]);
  } else if (i < N_WHH + N_WCAT) {
    int j = i - N_WHH; int n = j >> 8, k = j & 255;
    float v = 0.f;
    if (k < 208) v = (n < 768) ? w_ih[n * 209 + 1 + k] : w1[(n - 768) * 464 + 256 + k];
    Wcat[j] = f2bf(v);
  } else if (i < N_WHH + N_WCAT + N_W1H) {
    int j = i - N_WHH - N_WCAT; int n = j >> 8, k = j & 255;
    W1h[j] = f2bf(w1[n * 464 + k]);
  } else if (i < N_TOT) {
    int j = i - N_WHH - N_WCAT - N_W1H; int n = j >> 8, k = j & 255;
    W2b[j] = (n < 9) ? f2bf(w2[n * 256 + k]) : (unsigned short)0;
  }
}

// CST[row][1024]: cols 0..767 = cbm@Wih[:,1:]^T + b_ih (+b_hh for cols<512); cols 768..1023 = cbm@W1c^T + b1
__launch_bounds__(512, 2)
__global__ void const_kernel(const float* __restrict__ cc, const float* __restrict__ bb,
                             const float* __restrict__ mmat,
                             const float* __restrict__ b_ih, const float* __restrict__ b_hh,
                             const float* __restrict__ b1,
                             const unsigned short* __restrict__ Wcat,
                             float* __restrict__ CST, float* __restrict__ cnt) {
  __shared__ __align__(16) char smem[8192];
  const int tid = threadIdx.x;
  const int w = tid >> 6, l = tid & 63, q = l >> 4, li = l & 15;
  const int r0 = blockIdx.x << 4;

  // stage cbm = [c(80)|b(64)|m(64)|0..] bf16, swizzled
  {
    int row = tid >> 5, ch = tid & 31;
    float v[8];
#pragma unroll
    for (int j = 0; j < 8; j++) v[j] = 0.f;
    if (ch < 10) {
      const float* s = cc + (size_t)(r0 + row) * 80 + ch * 8;
#pragma unroll
      for (int j = 0; j < 8; j++) v[j] = s[j];
    } else if (ch < 18) {
      const float* s = bb + (size_t)(r0 + row) * 64 + (ch - 10) * 8;
#pragma unroll
      for (int j = 0; j < 8; j++) v[j] = s[j];
    } else if (ch < 26) {
      const float* s = mmat + (size_t)(r0 + row) * 64 + (ch - 18) * 8;
#pragma unroll
      for (int j = 0; j < 8; j++) v[j] = s[j];
    }
    short8 pk;
#pragma unroll
    for (int j = 0; j < 8; j++) pk[j] = (short)f2bf(v[j]);
    *(short8*)(smem + row * 512 + ((ch * 16) ^ ((row & 7) << 4))) = pk;
  }
  __syncthreads();

  int col[8];
  floatx4 acc[8];
#pragma unroll
  for (int tt = 0; tt < 8; tt++) {
    col[tt] = (w * 8 + tt) * 16 + li;
    float bv = (col[tt] < 768) ? (b_ih[col[tt]] + (col[tt] < 512 ? b_hh[col[tt]] : 0.f))
                               : b1[col[tt] - 768];
    acc[tt] = splat4(bv);
  }
#pragma unroll
  for (int kk = 0; kk < 7; kk++) {
    short8 a = *(const short8*)(smem + li * 512 + A_SW(kk, q, li));
#pragma unroll
    for (int tt = 0; tt < 8; tt++) {
      short8 bf = *(const short8*)(Wcat + (size_t)col[tt] * 256 + kk * 32 + q * 8);
      acc[tt] = __builtin_amdgcn_mfma_f32_16x16x32_bf16(a, bf, acc[tt], 0, 0, 0);
    }
  }
#pragma unroll
  for (int tt = 0; tt < 8; tt++)
#pragma unroll
    for (int r = 0; r < 4; r++)
      CST[(size_t)(r0 + q * 4 + r) * 1024 + col[tt]] = acc[tt][r];

  if (w == 0 && l < 16) {
    const float* bp = bb + (size_t)(r0 + l) * 64;
    const float* mp = mmat + (size_t)(r0 + l) * 64;
    float s = 0.f;
#pragma unroll 8
    for (int k2 = 0; k2 < 64; k2++) s += mp[k2] * (1.f - bp[k2]);
    cnt[r0 + l] = s;
  }
}

// GRU scan: Whh r/z in VGPRs, n-gate in LDS. Writes hs images (swizzled bf16) per step.
// LDS: WN @0 (128KB), H dbuf @131072 (2x8KB), Z @147456 (4KB)
__launch_bounds__(512, 2)
__global__ void gru_kernel(const float* __restrict__ z, const float* __restrict__ w_ih,
                           const float* __restrict__ b_hh,
                           const unsigned short* __restrict__ Whh,
                           const float* __restrict__ CST,
                           char* __restrict__ hs) {
  __shared__ __align__(16) char smem[151552];
  const int tid = threadIdx.x;
  const int w = tid >> 6, l = tid & 63, q = l >> 4, li = l & 15;
  const int r0 = blockIdx.x << 4;

  // stage n-gate Whh (rows 512..767) into LDS, swizzled
#pragma unroll
  for (int c = tid; c < 8192; c += 512) {
    int i = c >> 5, j = c & 31;
    short8 v = *(const short8*)(Whh + (size_t)(512 + i) * 256 + j * 8);
    *(short8*)(smem + i * 512 + ((j * 16) ^ ((i & 7) << 4))) = v;
  }
  // zero h slot 0
  *(floatx4*)(smem + 131072 + tid * 16) = splat4(0.f);
  // stage z rows
  {
    float* zb = (float*)(smem + 147456);
    zb[tid] = z[(size_t)r0 * 64 + tid];
    zb[tid + 512] = z[(size_t)r0 * 64 + 512 + tid];
  }

  int ncol6[6];
#pragma unroll
  for (int tt = 0; tt < 6; tt++) ncol6[tt] = (tt >> 1) * 256 + (w << 5) + ((tt & 1) << 4) + li;

  short8 wreg[4][8];   // r,z gate weights (tiles 0..3)
#pragma unroll
  for (int u4 = 0; u4 < 4; u4++)
#pragma unroll
    for (int kk = 0; kk < 8; kk++)
      wreg[u4][kk] = *(const short8*)(Whh + (size_t)ncol6[u4] * 256 + kk * 32 + q * 8);

  floatx4 cst[6];
#pragma unroll
  for (int tt = 0; tt < 6; tt++)
#pragma unroll
    for (int r = 0; r < 4; r++)
      cst[tt][r] = CST[(size_t)(r0 + q * 4 + r) * 1024 + ncol6[tt]];

  float wz[6];
#pragma unroll
  for (int tt = 0; tt < 6; tt++) wz[tt] = w_ih[(size_t)ncol6[tt] * 209];
  float bhhn[2];
#pragma unroll
  for (int nc = 0; nc < 2; nc++) bhhn[nc] = b_hh[ncol6[4 + nc]];

  float hreg[8];
#pragma unroll
  for (int j = 0; j < 8; j++) hreg[j] = 0.f;

  __syncthreads();
  char* hs_blk = hs + (size_t)blockIdx.x * 524288;

#pragma unroll 1
  for (int t = 0; t < 64; t++) {
    const char* hp = smem + 131072 + (t & 1) * 8192;
    char* hc = smem + 131072 + ((t + 1) & 1) * 8192;

    floatx4 acc[6];
#pragma unroll
    for (int u4 = 0; u4 < 4; u4++) acc[u4] = splat4(0.f);
#pragma unroll
    for (int nc = 0; nc < 2; nc++) acc[4 + nc] = splat4(bhhn[nc]);

#pragma unroll
    for (int kk = 0; kk < 8; kk++) {
      short8 a = *(const short8*)(hp + li * 512 + A_SW(kk, q, li));
      acc[0] = __builtin_amdgcn_mfma_f32_16x16x32_bf16(a, wreg[0][kk], acc[0], 0, 0, 0);
      acc[1] = __builtin_amdgcn_mfma_f32_16x16x32_bf16(a, wreg[1][kk], acc[1], 0, 0, 0);
      acc[2] = __builtin_amdgcn_mfma_f32_16x16x32_bf16(a, wreg[2][kk], acc[2], 0, 0, 0);
      acc[3] = __builtin_amdgcn_mfma_f32_16x16x32_bf16(a, wreg[3][kk], acc[3], 0, 0, 0);
#pragma unroll
      for (int nc = 0; nc < 2; nc++) {
        int i = (w << 5) + (nc << 4) + li;
        short8 bn = *(const short8*)(smem + i * 512 + A_SW(kk, q, i));
        acc[4 + nc] = __builtin_amdgcn_mfma_f32_16x16x32_bf16(a, bn, acc[4 + nc], 0, 0, 0);
      }
    }

    float zp[4];
    {
      const float* zb = (const float*)(smem + 147456);
      int tz = t ? (t - 1) : 0;
#pragma unroll
      for (int r = 0; r < 4; r++) {
        float zl = zb[(q * 4 + r) * 64 + tz];
        zp[r] = t ? zl : -1.f;
      }
    }

#pragma unroll
    for (int nc = 0; nc < 2; nc++) {
#pragma unroll
      for (int r = 0; r < 4; r++) {
        float gi_r = fmaf(zp[r], wz[nc],     cst[nc][r]);
        float gi_z = fmaf(zp[r], wz[2 + nc], cst[2 + nc][r]);
        float gi_n = fmaf(zp[r], wz[4 + nc], cst[4 + nc][r]);
        float rr = sigm_f(gi_r + acc[nc][r]);
        float zg = sigm_f(gi_z + acc[2 + nc][r]);
        float nn = tanh_f(fmaf(rr, acc[4 + nc][r], gi_n));
        float hv = fmaf(zg, hreg[nc * 4 + r] - nn, nn);
        hreg[nc * 4 + r] = hv;
        int rw = q * 4 + r;
        int colb = ((w << 5) + (nc << 4) + li) << 1;
        *(unsigned short*)(hc + rw * 512 + (colb ^ ((rw & 7) << 4))) = f2bf(hv);
      }
    }
    __syncthreads();
    // dump swizzled image to global (linear copy)
    short8 hv8 = *(const short8*)(hc + tid * 16);
    *(short8*)(hs_blk + (size_t)t * 8192 + tid * 16) = hv8;
  }
}

// MLP + GMM: 1024 blocks = 256 rowgroups x 4 tgroups; block = 16 rows x 16 t
// LDS: A dbuf @0 (2x8KB), U dbuf @16384 (2x8KB), P @32768 (8x1088), F @41472 (512)
__launch_bounds__(512, 4)
__global__ void mlp_kernel(const float* __restrict__ z, const float* __restrict__ b2,
                           const float* __restrict__ cnt,
                           const unsigned short* __restrict__ W1h,
                           const unsigned short* __restrict__ W2b,
                           const float* __restrict__ CST, const char* __restrict__ hs,
                           float* __restrict__ part) {
  __shared__ __align__(16) char smem[41984];
  const int tid = threadIdx.x;
  const int w = tid >> 6, l = tid & 63, q = l >> 4, li = l & 15;
  const int rg = blockIdx.x >> 2, tg = blockIdx.x & 3;
  const int r0 = rg << 4, t0 = tg << 4;
  const char* img = hs + (size_t)rg * 524288;

  int col[2];
#pragma unroll
  for (int nc = 0; nc < 2; nc++) col[nc] = (w << 5) + (nc << 4) + li;

  short8 w1reg[2][8];
#pragma unroll
  for (int nc = 0; nc < 2; nc++)
#pragma unroll
    for (int kk = 0; kk < 8; kk++)
      w1reg[nc][kk] = *(const short8*)(W1h + (size_t)col[nc] * 256 + kk * 32 + q * 8);

  float cst1[2][4];
#pragma unroll
  for (int nc = 0; nc < 2; nc++)
#pragma unroll
    for (int r = 0; r < 4; r++)
      cst1[nc][r] = CST[(size_t)(r0 + q * 4 + r) * 1024 + 768 + col[nc]];

  float b2v = (li < 9) ? b2[li] : 0.f;
  float cl = (l < 16) ? cnt[r0 + l] : 0.f;
  float lacc = 0.f;

  // stage A slot 0
  {
    short8 v = *(const short8*)(img + (size_t)t0 * 8192 + tid * 16);
    *(short8*)(smem + tid * 16) = v;
  }
  __syncthreads();

#pragma unroll 1
  for (int s = 0; s < 16; s++) {
    int t = t0 + s;
    if (s < 15) {  // prefetch next image into the other slot
      short8 v = *(const short8*)(img + (size_t)(t + 1) * 8192 + tid * 16);
      *(short8*)(smem + ((s + 1) & 1) * 8192 + tid * 16) = v;
    }
    floatx4 acc[2];
    acc[0] = splat4(0.f); acc[1] = splat4(0.f);
    const char* As = smem + (s & 1) * 8192;
#pragma unroll
    for (int kk = 0; kk < 8; kk++) {
      short8 a = *(const short8*)(As + li * 512 + A_SW(kk, q, li));
      acc[0] = __builtin_amdgcn_mfma_f32_16x16x32_bf16(a, w1reg[0][kk], acc[0], 0, 0, 0);
      acc[1] = __builtin_amdgcn_mfma_f32_16x16x32_bf16(a, w1reg[1][kk], acc[1], 0, 0, 0);
    }
    char* Us = smem + 16384 + (s & 1) * 8192;
#pragma unroll
    for (int nc = 0; nc < 2; nc++)
#pragma unroll
      for (int r = 0; r < 4; r++) {
        float uv = tanh_f(acc[nc][r] + cst1[nc][r]);
        int rw = q * 4 + r;
        int colb = col[nc] << 1;
        *(unsigned short*)(Us + rw * 512 + (colb ^ ((rw & 7) << 4))) = f2bf(uv);
      }
    __syncthreads();

    if (w == (s & 7)) {   // duty wave: w2 GEMM + GMM epilogue for this t
      floatx4 pacc = splat4(b2v);
#pragma unroll
      for (int kk = 0; kk < 8; kk++) {
        short8 au = *(const short8*)(Us + li * 512 + A_SW(kk, q, li));
        short8 bw = *(const short8*)(W2b + (size_t)li * 256 + kk * 32 + q * 8);
        pacc = __builtin_amdgcn_mfma_f32_16x16x32_bf16(au, bw, pacc, 0, 0, 0);
      }
      float* Pw = (float*)(smem + 32768 + w * 1088);
#pragma unroll
      for (int r = 0; r < 4; r++) Pw[(q * 4 + r) * 17 + li] = pacc[r];
      if (l < 16) {
        const float* pr = Pw + l * 17;
        float zt = z[(size_t)(r0 + l) * 64 + t];
        float aj[3], lg[3];
#pragma unroll
        for (int j = 0; j < 3; j++) {
          float lgt = pr[j];
          float mean = pr[3 + j];
          float ls = pr[6 + j];
          float d = (zt - mean) * __expf(-ls);
          lg[j] = lgt;
          aj[j] = lgt - ls - 0.9189385332f - 0.5f * d * d;
        }
        float mx = fmaxf(aj[0], fmaxf(aj[1], aj[2]));
        float ln_n = mx + __logf(__expf(aj[0] - mx) + __expf(aj[1] - mx) + __expf(aj[2] - mx));
        float mg = fmaxf(lg[0], fmaxf(lg[1], lg[2]));
        float ln_d = mg + __logf(__expf(lg[0] - mg) + __expf(lg[1] - mg) + __expf(lg[2] - mg));
        if ((float)t + 0.5f < cl) lacc += (ln_n - ln_d);
      }
    }
  }

  if (l < 16) ((float*)(smem + 41472))[w * 16 + l] = lacc;
  __syncthreads();
  if (w == 0 && l < 16) {
    const float* F = (const float*)(smem + 41472);
    float s = 0.f;
#pragma unroll
    for (int ww = 0; ww < 8; ww++) s += F[ww * 16 + l];
    part[rg * 64 + tg * 16 + l] = s;
  }
}

__global__ void reduce_kernel(const float* __restrict__ part, float* __restrict__ out) {
  int i = blockIdx.x * 256 + threadIdx.x;
  if (i < 4096) {
    int rg = i >> 4, row = i & 15;
    const float* p = part + rg * 64 + row;
    out[i] = p[0] + p[16] + p[32] + p[48];
  }
}

extern "C" void kernel_launch(void* const* d_in, const int* in_sizes, int n_in,
                              void* d_out, int out_size, void* d_ws, size_t ws_size,
                              hipStream_t stream) {
  const float* z    = (const float*)d_in[0];
  const float* c    = (const float*)d_in[1];
  const float* b    = (const float*)d_in[2];
  const float* m    = (const float*)d_in[3];
  const float* w_ih = (const float*)d_in[4];
  const float* w_hh = (const float*)d_in[5];
  const float* b_ih = (const float*)d_in[6];
  const float* b_hh = (const float*)d_in[7];
  const float* w1   = (const float*)d_in[8];
  const float* b1   = (const float*)d_in[9];
  const float* w2   = (const float*)d_in[10];
  const float* b2   = (const float*)d_in[11];

  char* ws = (char*)d_ws;
  unsigned short* Whh  = (unsigned short*)(ws);
  unsigned short* Wcat = (unsigned short*)(ws + 393216);
  unsigned short* W1h  = (unsigned short*)(ws + 917504);
  unsigned short* W2b  = (unsigned short*)(ws + 1048576);
  float*          CST  = (float*)(ws + 1056768);
  float*          cnt  = (float*)(ws + 17833984);
  float*          part = (float*)(ws + 17850368);
  char*           hs   = ws + 17915904;

  hipLaunchKernelGGL(prep_kernel, dim3(N_TOT / 256), dim3(256), 0, stream,
                     w_hh, w_ih, w1, w2, Whh, Wcat, W1h, W2b);
  hipLaunchKernelGGL(const_kernel, dim3(256), dim3(512), 0, stream,
                     c, b, m, b_ih, b_hh, b1, Wcat, CST, cnt);
  hipLaunchKernelGGL(gru_kernel, dim3(256), dim3(512), 0, stream,
                     z, w_ih, b_hh, Whh, CST, hs);
  hipLaunchKernelGGL(mlp_kernel, dim3(1024), dim3(512), 0, stream,
                     z, b2, cnt, W1h, W2b, CST, hs, part);
  hipLaunchKernelGGL(reduce_kernel, dim3(16), dim3(256), 0, stream,
                     part, (float*)d_out);
}

// Round 3
// 253.285 us; speedup vs baseline: 3.4316x; 1.4590x over previous
//
#include <hip/hip_runtime.h>

typedef __attribute__((ext_vector_type(8))) short short8;
typedef __attribute__((ext_vector_type(4))) float floatx4;

#define LOG2E     1.4426950408889634f
#define TWO_LOG2E 2.8853900817779268f

__device__ __forceinline__ unsigned short f2bf(float x) {
  union { float f; unsigned u; } v; v.f = x;
  unsigned r = v.u + 0x7fffu + ((v.u >> 16) & 1u);
  return (unsigned short)(r >> 16);
}
// s pre-scaled by log2e: sigmoid(x) = 1/(1+2^-s)
__device__ __forceinline__ float sigm_fast(float s) {
  return __builtin_amdgcn_rcpf(1.f + __builtin_amdgcn_exp2f(-s));
}
// y pre-scaled by 2*log2e: tanh(x) = 1 - 2/(1+2^y)
__device__ __forceinline__ float tanh_fast(float y) {
  return fmaf(-2.f, __builtin_amdgcn_rcpf(1.f + __builtin_amdgcn_exp2f(y)), 1.f);
}
__device__ __forceinline__ floatx4 splat4(float v) { floatx4 r; r[0]=v; r[1]=v; r[2]=v; r[3]=v; return r; }

#define N_WHH  (768*256)
#define N_WCAT (1024*256)
#define N_W1H  (256*256)
#define N_W2   (16*256)
#define N_TOT  (N_WHH + N_WCAT + N_W1H + N_W2)

// row swizzle: 4 q-groups of h-writes land in disjoint bank groups; A-reads stay balanced
#define GROW(r) (((((r)&7) ^ ((((r)>>3)&1)*5))) << 4)
#define A_SW(kk,q,row) ((((kk)<<6)+((q)<<4)) ^ GROW(row))

// bf16 weight staging, pre-scaled for exp2-form gates:
// rows feeding sigmoid (r,z): *log2e ; rows feeding tanh (n, w1): *2log2e
__global__ void prep_kernel(const float* __restrict__ w_hh, const float* __restrict__ w_ih,
                            const float* __restrict__ w1,  const float* __restrict__ w2,
                            unsigned short* __restrict__ Whh, unsigned short* __restrict__ Wcat,
                            unsigned short* __restrict__ W1h, unsigned short* __restrict__ W2b) {
  int i = blockIdx.x * blockDim.x + threadIdx.x;
  if (i < N_WHH) {
    int n = i >> 8;
    Whh[i] = f2bf(w_hh[i] * (n < 512 ? LOG2E : TWO_LOG2E));
  } else if (i < N_WHH + N_WCAT) {
    int j = i - N_WHH; int n = j >> 8, k = j & 255;
    float v = 0.f;
    if (k < 208) {
      if (n < 768) v = w_ih[n * 209 + 1 + k] * (n < 512 ? LOG2E : TWO_LOG2E);
      else         v = w1[(n - 768) * 464 + 256 + k] * TWO_LOG2E;
    }
    Wcat[j] = f2bf(v);
  } else if (i < N_WHH + N_WCAT + N_W1H) {
    int j = i - N_WHH - N_WCAT; int n = j >> 8, k = j & 255;
    W1h[j] = f2bf(w1[n * 464 + k] * TWO_LOG2E);
  } else if (i < N_TOT) {
    int j = i - N_WHH - N_WCAT - N_W1H; int n = j >> 8, k = j & 255;
    W2b[j] = (n < 9) ? f2bf(w2[n * 256 + k]) : (unsigned short)0;
  }
}

// CST[row][1024] (pre-scaled): 0..511 = log2e*(i_rz + b_ih + b_hh); 512..767 = 2log2e*(i_n + b_ih);
// 768..1023 = 2log2e*(cbm@W1c^T + b1). Also cnt[] and per-block cntmax[].
__launch_bounds__(512, 2)
__global__ void const_kernel(const float* __restrict__ cc, const float* __restrict__ bb,
                             const float* __restrict__ mmat,
                             const float* __restrict__ b_ih, const float* __restrict__ b_hh,
                             const float* __restrict__ b1,
                             const unsigned short* __restrict__ Wcat,
                             float* __restrict__ CST, float* __restrict__ cnt,
                             float* __restrict__ cntmax) {
  __shared__ __align__(16) char smem[8192];
  const int tid = threadIdx.x;
  const int w = tid >> 6, l = tid & 63, q = l >> 4, li = l & 15;
  const int r0 = blockIdx.x << 4;

  {
    int row = tid >> 5, ch = tid & 31;
    float v[8];
#pragma unroll
    for (int j = 0; j < 8; j++) v[j] = 0.f;
    if (ch < 10) {
      const float* s = cc + (size_t)(r0 + row) * 80 + ch * 8;
#pragma unroll
      for (int j = 0; j < 8; j++) v[j] = s[j];
    } else if (ch < 18) {
      const float* s = bb + (size_t)(r0 + row) * 64 + (ch - 10) * 8;
#pragma unroll
      for (int j = 0; j < 8; j++) v[j] = s[j];
    } else if (ch < 26) {
      const float* s = mmat + (size_t)(r0 + row) * 64 + (ch - 18) * 8;
#pragma unroll
      for (int j = 0; j < 8; j++) v[j] = s[j];
    }
    short8 pk;
#pragma unroll
    for (int j = 0; j < 8; j++) pk[j] = (short)f2bf(v[j]);
    *(short8*)(smem + row * 512 + ((ch * 16) ^ GROW(row))) = pk;
  }
  __syncthreads();

  int col[8];
  floatx4 acc[8];
#pragma unroll
  for (int tt = 0; tt < 8; tt++) {
    col[tt] = (w * 8 + tt) * 16 + li;
    float bv;
    if (col[tt] < 512)      bv = LOG2E * (b_ih[col[tt]] + b_hh[col[tt]]);
    else if (col[tt] < 768) bv = TWO_LOG2E * b_ih[col[tt]];
    else                    bv = TWO_LOG2E * b1[col[tt] - 768];
    acc[tt] = splat4(bv);
  }
#pragma unroll
  for (int kk = 0; kk < 7; kk++) {
    short8 a = *(const short8*)(smem + li * 512 + A_SW(kk, q, li));
#pragma unroll
    for (int tt = 0; tt < 8; tt++) {
      short8 bf = *(const short8*)(Wcat + (size_t)col[tt] * 256 + kk * 32 + q * 8);
      acc[tt] = __builtin_amdgcn_mfma_f32_16x16x32_bf16(a, bf, acc[tt], 0, 0, 0);
    }
  }
#pragma unroll
  for (int tt = 0; tt < 8; tt++)
#pragma unroll
    for (int r = 0; r < 4; r++)
      CST[(size_t)(r0 + q * 4 + r) * 1024 + col[tt]] = acc[tt][r];

  if (w == 0 && l < 16) {
    const float* bp = bb + (size_t)(r0 + l) * 64;
    const float* mp = mmat + (size_t)(r0 + l) * 64;
    float s = 0.f;
#pragma unroll 8
    for (int k2 = 0; k2 < 64; k2++) s += mp[k2] * (1.f - bp[k2]);
    cnt[r0 + l] = s;
    float mx = s;
#pragma unroll
    for (int off = 8; off; off >>= 1) mx = fmaxf(mx, __shfl_xor(mx, off, 16));
    if (l == 0) cntmax[blockIdx.x] = mx;
  }
}

// GRU scan, terminated at the block's cnt-max.
// LDS: WN (n-gate weights, swizzled) @0 128KB, H dbuf @131072 2x8KB, Z transposed @147456 4KB
__launch_bounds__(512, 2)
__global__ void gru_kernel(const float* __restrict__ z, const float* __restrict__ w_ih,
                           const float* __restrict__ b_hh,
                           const unsigned short* __restrict__ Whh,
                           const float* __restrict__ CST,
                           const float* __restrict__ cntmax,
                           char* __restrict__ hs) {
  __shared__ __align__(16) char smem[151552];
  const int tid = threadIdx.x;
  const int w = tid >> 6, l = tid & 63, q = l >> 4, li = l & 15;
  const int r0 = blockIdx.x << 4;
  const int nsteps = (int)(cntmax[blockIdx.x] + 0.5f);

#pragma unroll
  for (int c = tid; c < 8192; c += 512) {
    int i = c >> 5, j = c & 31;
    short8 v = *(const short8*)(Whh + (size_t)(512 + i) * 256 + j * 8);
    *(short8*)(smem + i * 512 + ((j * 16) ^ GROW(i))) = v;
  }
  *(floatx4*)(smem + 131072 + tid * 16) = splat4(0.f);
  {
    float* zb = (float*)(smem + 147456);
    int i0 = tid;
    zb[i0] = z[(size_t)(r0 + (i0 & 15)) * 64 + (i0 >> 4)];
    int i1 = tid + 512;
    zb[i1] = z[(size_t)(r0 + (i1 & 15)) * 64 + (i1 >> 4)];
  }

  int ncol6[6];
#pragma unroll
  for (int tt = 0; tt < 6; tt++) ncol6[tt] = (tt >> 1) * 256 + (w << 5) + ((tt & 1) << 4) + li;

  short8 wreg[4][8];   // r,z gate weights in VGPRs
#pragma unroll
  for (int u4 = 0; u4 < 4; u4++)
#pragma unroll
    for (int kk = 0; kk < 8; kk++)
      wreg[u4][kk] = *(const short8*)(Whh + (size_t)ncol6[u4] * 256 + kk * 32 + q * 8);

  floatx4 cst[6];
#pragma unroll
  for (int tt = 0; tt < 6; tt++)
#pragma unroll
    for (int r = 0; r < 4; r++)
      cst[tt][r] = CST[(size_t)(r0 + q * 4 + r) * 1024 + ncol6[tt]];

  float wz[6];
#pragma unroll
  for (int tt = 0; tt < 6; tt++)
    wz[tt] = w_ih[(size_t)ncol6[tt] * 209] * (tt < 4 ? LOG2E : TWO_LOG2E);
  float bhhn[2];
#pragma unroll
  for (int nc = 0; nc < 2; nc++) bhhn[nc] = b_hh[ncol6[4 + nc]] * TWO_LOG2E;

  float hreg[8];
#pragma unroll
  for (int j = 0; j < 8; j++) hreg[j] = 0.f;

  __syncthreads();
  char* hs_blk = hs + (size_t)blockIdx.x * 524288;

#pragma unroll 1
  for (int t = 0; t < nsteps; t++) {
    const char* hp = smem + 131072 + (t & 1) * 8192;
    char* hc = smem + 131072 + ((t + 1) & 1) * 8192;

    floatx4 acc[6];
#pragma unroll
    for (int u4 = 0; u4 < 4; u4++) acc[u4] = splat4(0.f);
#pragma unroll
    for (int nc = 0; nc < 2; nc++) acc[4 + nc] = splat4(bhhn[nc]);

#pragma unroll
    for (int kk = 0; kk < 8; kk++) {
      short8 a = *(const short8*)(hp + li * 512 + A_SW(kk, q, li));
      acc[0] = __builtin_amdgcn_mfma_f32_16x16x32_bf16(a, wreg[0][kk], acc[0], 0, 0, 0);
      acc[1] = __builtin_amdgcn_mfma_f32_16x16x32_bf16(a, wreg[1][kk], acc[1], 0, 0, 0);
      acc[2] = __builtin_amdgcn_mfma_f32_16x16x32_bf16(a, wreg[2][kk], acc[2], 0, 0, 0);
      acc[3] = __builtin_amdgcn_mfma_f32_16x16x32_bf16(a, wreg[3][kk], acc[3], 0, 0, 0);
#pragma unroll
      for (int nc = 0; nc < 2; nc++) {
        int i = (w << 5) + (nc << 4) + li;
        short8 bn = *(const short8*)(smem + i * 512 + A_SW(kk, q, i));
        acc[4 + nc] = __builtin_amdgcn_mfma_f32_16x16x32_bf16(a, bn, acc[4 + nc], 0, 0, 0);
      }
    }

    floatx4 zpv;
    if (t == 0) zpv = splat4(-1.f);
    else        zpv = *(const floatx4*)(smem + 147456 + (t - 1) * 64 + (q << 4));

#pragma unroll
    for (int nc = 0; nc < 2; nc++) {
#pragma unroll
      for (int r = 0; r < 4; r++) {
        float rr = sigm_fast(fmaf(zpv[r], wz[nc],     cst[nc][r])     + acc[nc][r]);
        float zg = sigm_fast(fmaf(zpv[r], wz[2 + nc], cst[2 + nc][r]) + acc[2 + nc][r]);
        float nn = tanh_fast(fmaf(rr, acc[4 + nc][r],
                                  fmaf(zpv[r], wz[4 + nc], cst[4 + nc][r])));
        float hv = fmaf(zg, hreg[nc * 4 + r] - nn, nn);
        hreg[nc * 4 + r] = hv;
        int rw = (q << 2) + r;
        int colb = ((w << 5) + (nc << 4) + li) << 1;
        *(unsigned short*)(hc + rw * 512 + (colb ^ GROW(rw))) = f2bf(hv);
      }
    }
    __syncthreads();   // single barrier: dbuf makes pre-write barrier redundant
    *(short8*)(hs_blk + (size_t)t * 8192 + tid * 16) = *(const short8*)(hc + tid * 16);
  }
}

// MLP + GMM, bounded by per-rowgroup cnt-max.
// LDS: A dbuf @0 2x8KB, U dbuf @16384 2x8KB, P shared @32768 1088B (F reuses P)
__launch_bounds__(512, 4)
__global__ void mlp_kernel(const float* __restrict__ z, const float* __restrict__ b2,
                           const float* __restrict__ cnt, const float* __restrict__ cntmax,
                           const unsigned short* __restrict__ W1h,
                           const unsigned short* __restrict__ W2b,
                           const float* __restrict__ CST, const char* __restrict__ hs,
                           float* __restrict__ part) {
  __shared__ __align__(16) char smem[33856];
  const int tid = threadIdx.x;
  const int w = tid >> 6, l = tid & 63, q = l >> 4, li = l & 15;
  const int rg = blockIdx.x >> 2, tg = blockIdx.x & 3;
  const int r0 = rg << 4, t0 = tg << 4;

  const int nsteps = (int)(cntmax[rg] + 0.5f);
  int tend = nsteps - t0; if (tend > 16) tend = 16;
  if (tend <= 0) {
    if (tid < 16) part[rg * 64 + tg * 16 + tid] = 0.f;
    return;
  }
  const char* img = hs + (size_t)rg * 524288;

  int col[2];
#pragma unroll
  for (int nc = 0; nc < 2; nc++) col[nc] = (w << 5) + (nc << 4) + li;

  short8 w1reg[2][8];
#pragma unroll
  for (int nc = 0; nc < 2; nc++)
#pragma unroll
    for (int kk = 0; kk < 8; kk++)
      w1reg[nc][kk] = *(const short8*)(W1h + (size_t)col[nc] * 256 + kk * 32 + q * 8);

  float cst1[2][4];
#pragma unroll
  for (int nc = 0; nc < 2; nc++)
#pragma unroll
    for (int r = 0; r < 4; r++)
      cst1[nc][r] = CST[(size_t)(r0 + q * 4 + r) * 1024 + 768 + col[nc]];

  float b2v = (li < 9) ? b2[li] : 0.f;
  float cl = (l < 16) ? cnt[r0 + l] : 0.f;
  float lacc = 0.f;

  {
    short8 v = *(const short8*)(img + (size_t)t0 * 8192 + tid * 16);
    *(short8*)(smem + tid * 16) = v;
  }
  __syncthreads();

#pragma unroll 1
  for (int s = 0; s < tend; s++) {
    int t = t0 + s;
    if (s + 1 < tend) {
      short8 v = *(const short8*)(img + (size_t)(t + 1) * 8192 + tid * 16);
      *(short8*)(smem + ((s + 1) & 1) * 8192 + tid * 16) = v;
    }
    floatx4 acc[2];
    acc[0] = splat4(0.f); acc[1] = splat4(0.f);
    const char* As = smem + (s & 1) * 8192;
#pragma unroll
    for (int kk = 0; kk < 8; kk++) {
      short8 a = *(const short8*)(As + li * 512 + A_SW(kk, q, li));
      acc[0] = __builtin_amdgcn_mfma_f32_16x16x32_bf16(a, w1reg[0][kk], acc[0], 0, 0, 0);
      acc[1] = __builtin_amdgcn_mfma_f32_16x16x32_bf16(a, w1reg[1][kk], acc[1], 0, 0, 0);
    }
    char* Us = smem + 16384 + (s & 1) * 8192;
#pragma unroll
    for (int nc = 0; nc < 2; nc++)
#pragma unroll
      for (int r = 0; r < 4; r++) {
        float uv = tanh_fast(acc[nc][r] + cst1[nc][r]);
        int rw = (q << 2) + r;
        int colb = col[nc] << 1;
        *(unsigned short*)(Us + rw * 512 + (colb ^ GROW(rw))) = f2bf(uv);
      }
    __syncthreads();

    if (w == (s & 7)) {
      floatx4 pacc = splat4(b2v);
#pragma unroll
      for (int kk = 0; kk < 8; kk++) {
        short8 au = *(const short8*)(Us + li * 512 + A_SW(kk, q, li));
        short8 bw = *(const short8*)(W2b + (size_t)li * 256 + kk * 32 + q * 8);
        pacc = __builtin_amdgcn_mfma_f32_16x16x32_bf16(au, bw, pacc, 0, 0, 0);
      }
      float* Pw = (float*)(smem + 32768);
#pragma unroll
      for (int r = 0; r < 4; r++) Pw[((q << 2) + r) * 17 + li] = pacc[r];
      if (l < 16) {
        const float* pr = Pw + l * 17;
        float zt = z[(size_t)(r0 + l) * 64 + t];
        float aj[3], lg[3];
#pragma unroll
        for (int j = 0; j < 3; j++) {
          float lgt = pr[j];
          float mean = pr[3 + j];
          float ls = pr[6 + j];
          float d = (zt - mean) * __expf(-ls);
          lg[j] = lgt;
          aj[j] = lgt - ls - 0.9189385332f - 0.5f * d * d;
        }
        float mx = fmaxf(aj[0], fmaxf(aj[1], aj[2]));
        float ln_n = mx + __logf(__expf(aj[0] - mx) + __expf(aj[1] - mx) + __expf(aj[2] - mx));
        float mg = fmaxf(lg[0], fmaxf(lg[1], lg[2]));
        float ln_d = mg + __logf(__expf(lg[0] - mg) + __expf(lg[1] - mg) + __expf(lg[2] - mg));
        if ((float)t + 0.5f < cl) lacc += (ln_n - ln_d);
      }
    }
  }

  __syncthreads();   // last duty wave done with P before F reuses it
  if (l < 16) ((float*)(smem + 32768))[w * 16 + l] = lacc;
  __syncthreads();
  if (w == 0 && l < 16) {
    const float* F = (const float*)(smem + 32768);
    float s = 0.f;
#pragma unroll
    for (int ww = 0; ww < 8; ww++) s += F[ww * 16 + l];
    part[rg * 64 + tg * 16 + l] = s;
  }
}

__global__ void reduce_kernel(const float* __restrict__ part, float* __restrict__ out) {
  int i = blockIdx.x * 256 + threadIdx.x;
  if (i < 4096) {
    int rg = i >> 4, row = i & 15;
    const float* p = part + rg * 64 + row;
    out[i] = p[0] + p[16] + p[32] + p[48];
  }
}

extern "C" void kernel_launch(void* const* d_in, const int* in_sizes, int n_in,
                              void* d_out, int out_size, void* d_ws, size_t ws_size,
                              hipStream_t stream) {
  const float* z    = (const float*)d_in[0];
  const float* c    = (const float*)d_in[1];
  const float* b    = (const float*)d_in[2];
  const float* m    = (const float*)d_in[3];
  const float* w_ih = (const float*)d_in[4];
  const float* w_hh = (const float*)d_in[5];
  const float* b_ih = (const float*)d_in[6];
  const float* b_hh = (const float*)d_in[7];
  const float* w1   = (const float*)d_in[8];
  const float* b1   = (const float*)d_in[9];
  const float* w2   = (const float*)d_in[10];
  const float* b2   = (const float*)d_in[11];

  char* ws = (char*)d_ws;
  unsigned short* Whh  = (unsigned short*)(ws);
  unsigned short* Wcat = (unsigned short*)(ws + 393216);
  unsigned short* W1h  = (unsigned short*)(ws + 917504);
  unsigned short* W2b  = (unsigned short*)(ws + 1048576);
  float*          CST  = (float*)(ws + 1056768);
  float*          cnt  = (float*)(ws + 17833984);
  float*          cmax = (float*)(ws + 17850368);
  float*          part = (float*)(ws + 17851392);
  char*           hs   = ws + 17916928;

  hipLaunchKernelGGL(prep_kernel, dim3(N_TOT / 256), dim3(256), 0, stream,
                     w_hh, w_ih, w1, w2, Whh, Wcat, W1h, W2b);
  hipLaunchKernelGGL(const_kernel, dim3(256), dim3(512), 0, stream,
                     c, b, m, b_ih, b_hh, b1, Wcat, CST, cnt, cmax);
  hipLaunchKernelGGL(gru_kernel, dim3(256), dim3(512), 0, stream,
                     z, w_ih, b_hh, Whh, CST, cmax, hs);
  hipLaunchKernelGGL(mlp_kernel, dim3(1024), dim3(512), 0, stream,
                     z, b2, cnt, cmax, W1h, W2b, CST, hs, part);
  hipLaunchKernelGGL(reduce_kernel, dim3(16), dim3(256), 0, stream,
                     part, (float*)d_out);
}

// Round 4
// 206.735 us; speedup vs baseline: 4.2043x; 1.2252x over previous
//
#include <hip/hip_runtime.h>

typedef __attribute__((ext_vector_type(8))) short short8;
typedef __attribute__((ext_vector_type(4))) float floatx4;

#define LOG2E     1.4426950408889634f
#define TWO_LOG2E 2.8853900817779268f

__device__ __forceinline__ unsigned short f2bf(float x) {
  union { float f; unsigned u; } v; v.f = x;
  unsigned r = v.u + 0x7fffu + ((v.u >> 16) & 1u);
  return (unsigned short)(r >> 16);
}
// s pre-scaled by log2e: sigmoid(x) = 1/(1+2^-s)
__device__ __forceinline__ float sigm_fast(float s) {
  return __builtin_amdgcn_rcpf(1.f + __builtin_amdgcn_exp2f(-s));
}
// y pre-scaled by 2*log2e: tanh(x) = 1 - 2/(1+2^y)
__device__ __forceinline__ float tanh_fast(float y) {
  return fmaf(-2.f, __builtin_amdgcn_rcpf(1.f + __builtin_amdgcn_exp2f(y)), 1.f);
}
__device__ __forceinline__ floatx4 splat4(float v) { floatx4 r; r[0]=v; r[1]=v; r[2]=v; r[3]=v; return r; }

#define N_WHH  (768*256)
#define N_WCAT (1024*256)
#define N_W1H  (256*256)
#define N_W2   (16*256)
#define N_TOT  (N_WHH + N_WCAT + N_W1H + N_W2)

#define GROW(r) (((((r)&7) ^ ((((r)>>3)&1)*5))) << 4)
#define A_SW(kk,q,row) ((((kk)<<6)+((q)<<4)) ^ GROW(row))

__global__ void prep_kernel(const float* __restrict__ w_hh, const float* __restrict__ w_ih,
                            const float* __restrict__ w1,  const float* __restrict__ w2,
                            unsigned short* __restrict__ Whh, unsigned short* __restrict__ Wcat,
                            unsigned short* __restrict__ W1h, unsigned short* __restrict__ W2b) {
  int i = blockIdx.x * blockDim.x + threadIdx.x;
  if (i < N_WHH) {
    int n = i >> 8;
    Whh[i] = f2bf(w_hh[i] * (n < 512 ? LOG2E : TWO_LOG2E));
  } else if (i < N_WHH + N_WCAT) {
    int j = i - N_WHH; int n = j >> 8, k = j & 255;
    float v = 0.f;
    if (k < 208) {
      if (n < 768) v = w_ih[n * 209 + 1 + k] * (n < 512 ? LOG2E : TWO_LOG2E);
      else         v = w1[(n - 768) * 464 + 256 + k] * TWO_LOG2E;
    }
    Wcat[j] = f2bf(v);
  } else if (i < N_WHH + N_WCAT + N_W1H) {
    int j = i - N_WHH - N_WCAT; int n = j >> 8, k = j & 255;
    W1h[j] = f2bf(w1[n * 464 + k] * TWO_LOG2E);
  } else if (i < N_TOT) {
    int j = i - N_WHH - N_WCAT - N_W1H; int n = j >> 8, k = j & 255;
    W2b[j] = (n < 9) ? f2bf(w2[n * 256 + k]) : (unsigned short)0;
  }
}

__launch_bounds__(512, 1)
__global__ void const_kernel(const float* __restrict__ cc, const float* __restrict__ bb,
                             const float* __restrict__ mmat,
                             const float* __restrict__ b_ih, const float* __restrict__ b_hh,
                             const float* __restrict__ b1,
                             const unsigned short* __restrict__ Wcat,
                             float* __restrict__ CST, float* __restrict__ cnt,
                             float* __restrict__ cntmax) {
  __shared__ __align__(16) char smem[8192];
  const int tid = threadIdx.x;
  const int w = tid >> 6, l = tid & 63, q = l >> 4, li = l & 15;
  const int r0 = blockIdx.x << 4;

  {
    int row = tid >> 5, ch = tid & 31;
    float v[8];
#pragma unroll
    for (int j = 0; j < 8; j++) v[j] = 0.f;
    if (ch < 10) {
      const float* s = cc + (size_t)(r0 + row) * 80 + ch * 8;
#pragma unroll
      for (int j = 0; j < 8; j++) v[j] = s[j];
    } else if (ch < 18) {
      const float* s = bb + (size_t)(r0 + row) * 64 + (ch - 10) * 8;
#pragma unroll
      for (int j = 0; j < 8; j++) v[j] = s[j];
    } else if (ch < 26) {
      const float* s = mmat + (size_t)(r0 + row) * 64 + (ch - 18) * 8;
#pragma unroll
      for (int j = 0; j < 8; j++) v[j] = s[j];
    }
    short8 pk;
#pragma unroll
    for (int j = 0; j < 8; j++) pk[j] = (short)f2bf(v[j]);
    *(short8*)(smem + row * 512 + ((ch * 16) ^ GROW(row))) = pk;
  }
  __syncthreads();

  int col[8];
  floatx4 acc[8];
#pragma unroll
  for (int tt = 0; tt < 8; tt++) {
    col[tt] = (w * 8 + tt) * 16 + li;
    float bv;
    if (col[tt] < 512)      bv = LOG2E * (b_ih[col[tt]] + b_hh[col[tt]]);
    else if (col[tt] < 768) bv = TWO_LOG2E * b_ih[col[tt]];
    else                    bv = TWO_LOG2E * b1[col[tt] - 768];
    acc[tt] = splat4(bv);
  }
#pragma unroll
  for (int kk = 0; kk < 7; kk++) {
    short8 a = *(const short8*)(smem + li * 512 + A_SW(kk, q, li));
#pragma unroll
    for (int tt = 0; tt < 8; tt++) {
      short8 bf = *(const short8*)(Wcat + (size_t)col[tt] * 256 + kk * 32 + q * 8);
      acc[tt] = __builtin_amdgcn_mfma_f32_16x16x32_bf16(a, bf, acc[tt], 0, 0, 0);
    }
  }
#pragma unroll
  for (int tt = 0; tt < 8; tt++)
#pragma unroll
    for (int r = 0; r < 4; r++)
      CST[(size_t)(r0 + q * 4 + r) * 1024 + col[tt]] = acc[tt][r];

  if (w == 0 && l < 16) {
    const float* bp = bb + (size_t)(r0 + l) * 64;
    const float* mp = mmat + (size_t)(r0 + l) * 64;
    float s = 0.f;
#pragma unroll 8
    for (int k2 = 0; k2 < 64; k2++) s += mp[k2] * (1.f - bp[k2]);
    cnt[r0 + l] = s;
    float mx = s;
#pragma unroll
    for (int off = 8; off; off >>= 1) mx = fmaxf(mx, __shfl_xor(mx, off, 16));
    if (l == 0) cntmax[blockIdx.x] = mx;
  }
}

// GRU scan, terminated at the block's cnt-max.
// LDS: WN @0 128KB, H dbuf @131072 2x8KB, Z transposed @147456 4KB
__launch_bounds__(512, 1)
__global__ void gru_kernel(const float* __restrict__ z, const float* __restrict__ w_ih,
                           const float* __restrict__ b_hh,
                           const unsigned short* __restrict__ Whh,
                           const float* __restrict__ CST,
                           const float* __restrict__ cntmax,
                           char* __restrict__ hs) {
  __shared__ __align__(16) char smem[151552];
  const int tid = threadIdx.x;
  const int w = tid >> 6, l = tid & 63, q = l >> 4, li = l & 15;
  const int r0 = blockIdx.x << 4;
  const int nsteps = (int)(cntmax[blockIdx.x] + 0.5f);

#pragma unroll
  for (int c = tid; c < 8192; c += 512) {
    int i = c >> 5, j = c & 31;
    short8 v = *(const short8*)(Whh + (size_t)(512 + i) * 256 + j * 8);
    *(short8*)(smem + i * 512 + ((j * 16) ^ GROW(i))) = v;
  }
  *(floatx4*)(smem + 131072 + tid * 16) = splat4(0.f);
  {
    float* zb = (float*)(smem + 147456);
    int i0 = tid;
    zb[i0] = z[(size_t)(r0 + (i0 & 15)) * 64 + (i0 >> 4)];
    int i1 = tid + 512;
    zb[i1] = z[(size_t)(r0 + (i1 & 15)) * 64 + (i1 >> 4)];
  }

  int ncol6[6];
#pragma unroll
  for (int tt = 0; tt < 6; tt++) ncol6[tt] = (tt >> 1) * 256 + (w << 5) + ((tt & 1) << 4) + li;

  short8 wreg[4][8];
#pragma unroll
  for (int u4 = 0; u4 < 4; u4++)
#pragma unroll
    for (int kk = 0; kk < 8; kk++)
      wreg[u4][kk] = *(const short8*)(Whh + (size_t)ncol6[u4] * 256 + kk * 32 + q * 8);

  floatx4 cst[6];
#pragma unroll
  for (int tt = 0; tt < 6; tt++)
#pragma unroll
    for (int r = 0; r < 4; r++)
      cst[tt][r] = CST[(size_t)(r0 + q * 4 + r) * 1024 + ncol6[tt]];

  float wz[6];
#pragma unroll
  for (int tt = 0; tt < 6; tt++)
    wz[tt] = w_ih[(size_t)ncol6[tt] * 209] * (tt < 4 ? LOG2E : TWO_LOG2E);
  float bhhn[2];
#pragma unroll
  for (int nc = 0; nc < 2; nc++) bhhn[nc] = b_hh[ncol6[4 + nc]] * TWO_LOG2E;

  float hreg[8];
#pragma unroll
  for (int j = 0; j < 8; j++) hreg[j] = 0.f;

  __syncthreads();
  char* hs_blk = hs + (size_t)blockIdx.x * 524288;

#pragma unroll 1
  for (int t = 0; t < nsteps; t++) {
    const char* hp = smem + 131072 + (t & 1) * 8192;
    char* hc = smem + 131072 + ((t + 1) & 1) * 8192;

    floatx4 acc[6];
#pragma unroll
    for (int u4 = 0; u4 < 4; u4++) acc[u4] = splat4(0.f);
#pragma unroll
    for (int nc = 0; nc < 2; nc++) acc[4 + nc] = splat4(bhhn[nc]);

#pragma unroll
    for (int kk = 0; kk < 8; kk++) {
      short8 a = *(const short8*)(hp + li * 512 + A_SW(kk, q, li));
      acc[0] = __builtin_amdgcn_mfma_f32_16x16x32_bf16(a, wreg[0][kk], acc[0], 0, 0, 0);
      acc[1] = __builtin_amdgcn_mfma_f32_16x16x32_bf16(a, wreg[1][kk], acc[1], 0, 0, 0);
      acc[2] = __builtin_amdgcn_mfma_f32_16x16x32_bf16(a, wreg[2][kk], acc[2], 0, 0, 0);
      acc[3] = __builtin_amdgcn_mfma_f32_16x16x32_bf16(a, wreg[3][kk], acc[3], 0, 0, 0);
#pragma unroll
      for (int nc = 0; nc < 2; nc++) {
        int i = (w << 5) + (nc << 4) + li;
        short8 bn = *(const short8*)(smem + i * 512 + A_SW(kk, q, i));
        acc[4 + nc] = __builtin_amdgcn_mfma_f32_16x16x32_bf16(a, bn, acc[4 + nc], 0, 0, 0);
      }
    }

    floatx4 zpv;
    if (t == 0) zpv = splat4(-1.f);
    else        zpv = *(const floatx4*)(smem + 147456 + (t - 1) * 64 + (q << 4));

#pragma unroll
    for (int nc = 0; nc < 2; nc++) {
#pragma unroll
      for (int r = 0; r < 4; r++) {
        float rr = sigm_fast(fmaf(zpv[r], wz[nc],     cst[nc][r])     + acc[nc][r]);
        float zg = sigm_fast(fmaf(zpv[r], wz[2 + nc], cst[2 + nc][r]) + acc[2 + nc][r]);
        float nn = tanh_fast(fmaf(rr, acc[4 + nc][r],
                                  fmaf(zpv[r], wz[4 + nc], cst[4 + nc][r])));
        float hv = fmaf(zg, hreg[nc * 4 + r] - nn, nn);
        hreg[nc * 4 + r] = hv;
        int rw = (q << 2) + r;
        int colb = ((w << 5) + (nc << 4) + li) << 1;
        *(unsigned short*)(hc + rw * 512 + (colb ^ GROW(rw))) = f2bf(hv);
      }
    }
    __syncthreads();
    *(short8*)(hs_blk + (size_t)t * 8192 + tid * 16) = *(const short8*)(hc + tid * 16);
  }
}

// MLP + GMM. Grid 512 = tg-outer (tg in {0,1}) x 256 rowgroups; t = tg + 2s.
// LDS: A dbuf @0 2x8KB, U dbuf @16384 2x8KB, P @32768 1088B (F reuses), zb @33920 2KB
__launch_bounds__(512, 2)
__global__ void mlp_kernel(const float* __restrict__ z, const float* __restrict__ b2,
                           const float* __restrict__ cnt, const float* __restrict__ cntmax,
                           const unsigned short* __restrict__ W1h,
                           const unsigned short* __restrict__ W2b,
                           const float* __restrict__ CST, const char* __restrict__ hs,
                           float* __restrict__ part) {
  __shared__ __align__(16) char smem[35968];
  const int tid = threadIdx.x;
  const int w = tid >> 6, l = tid & 63, q = l >> 4, li = l & 15;
  const int tg = blockIdx.x >> 8, rg = blockIdx.x & 255;
  const int r0 = rg << 4;

  const int nsteps = (int)(cntmax[rg] + 0.5f);
  const int count = (nsteps - tg + 1) >> 1;
  if (count <= 0) {
    if (tid < 16) part[rg * 32 + tg * 16 + tid] = 0.f;
    return;
  }
  const char* img = hs + (size_t)rg * 524288;

  // stage z tile transposed: zb[s*16+row] = z[row][tg+2s]
  {
    int s = tid >> 4, row = tid & 15;
    ((float*)(smem + 33920))[tid] = z[(size_t)(r0 + row) * 64 + tg + 2 * s];
  }

  int col[2];
#pragma unroll
  for (int nc = 0; nc < 2; nc++) col[nc] = (w << 5) + (nc << 4) + li;

  short8 w1reg[2][8];
#pragma unroll
  for (int nc = 0; nc < 2; nc++)
#pragma unroll
    for (int kk = 0; kk < 8; kk++)
      w1reg[nc][kk] = *(const short8*)(W1h + (size_t)col[nc] * 256 + kk * 32 + q * 8);

  float cst1[2][4];
#pragma unroll
  for (int nc = 0; nc < 2; nc++)
#pragma unroll
    for (int r = 0; r < 4; r++)
      cst1[nc][r] = CST[(size_t)(r0 + q * 4 + r) * 1024 + 768 + col[nc]];

  float b2v = (li < 9) ? b2[li] : 0.f;
  float cl = (l < 16) ? cnt[r0 + l] : 0.f;
  float lacc = 0.f;

  // stage A slot 0 (t = tg)
  {
    short8 v = *(const short8*)(img + (size_t)tg * 8192 + tid * 16);
    *(short8*)(smem + tid * 16) = v;
  }
  __syncthreads();

#pragma unroll 1
  for (int s = 0; s < count; s++) {
    int t = tg + 2 * s;
    // T14 split: issue next-image load now, ds_write after compute
    short8 pf;
    bool do_pf = (s + 1 < count);
    if (do_pf) pf = *(const short8*)(img + (size_t)(t + 2) * 8192 + tid * 16);

    floatx4 acc[2];
    acc[0] = splat4(0.f); acc[1] = splat4(0.f);
    const char* As = smem + (s & 1) * 8192;
#pragma unroll
    for (int kk = 0; kk < 8; kk++) {
      short8 a = *(const short8*)(As + li * 512 + A_SW(kk, q, li));
      acc[0] = __builtin_amdgcn_mfma_f32_16x16x32_bf16(a, w1reg[0][kk], acc[0], 0, 0, 0);
      acc[1] = __builtin_amdgcn_mfma_f32_16x16x32_bf16(a, w1reg[1][kk], acc[1], 0, 0, 0);
    }
    char* Us = smem + 16384 + (s & 1) * 8192;
#pragma unroll
    for (int nc = 0; nc < 2; nc++)
#pragma unroll
      for (int r = 0; r < 4; r++) {
        float uv = tanh_fast(acc[nc][r] + cst1[nc][r]);
        int rw = (q << 2) + r;
        int colb = col[nc] << 1;
        *(unsigned short*)(Us + rw * 512 + (colb ^ GROW(rw))) = f2bf(uv);
      }
    if (do_pf) *(short8*)(smem + ((s + 1) & 1) * 8192 + tid * 16) = pf;
    __syncthreads();

    if (w == (s & 7)) {   // duty wave: w2 GEMM + GMM epilogue
      floatx4 pacc = splat4(b2v);
#pragma unroll
      for (int kk = 0; kk < 8; kk++) {
        short8 au = *(const short8*)(Us + li * 512 + A_SW(kk, q, li));
        short8 bw = *(const short8*)(W2b + (size_t)li * 256 + kk * 32 + q * 8);
        pacc = __builtin_amdgcn_mfma_f32_16x16x32_bf16(au, bw, pacc, 0, 0, 0);
      }
      float* Pw = (float*)(smem + 32768);
#pragma unroll
      for (int r = 0; r < 4; r++) Pw[((q << 2) + r) * 17 + li] = pacc[r];
      if (l < 16) {
        const float* pr = Pw + l * 17;
        float zt = ((const float*)(smem + 33920))[s * 16 + l];
        float aj[3], lg[3];
#pragma unroll
        for (int j = 0; j < 3; j++) {
          float lgt = pr[j];
          float mean = pr[3 + j];
          float ls = pr[6 + j];
          float d = (zt - mean) * __expf(-ls);
          lg[j] = lgt;
          aj[j] = lgt - ls - 0.9189385332f - 0.5f * d * d;
        }
        float mx = fmaxf(aj[0], fmaxf(aj[1], aj[2]));
        float ln_n = mx + __logf(__expf(aj[0] - mx) + __expf(aj[1] - mx) + __expf(aj[2] - mx));
        float mg = fmaxf(lg[0], fmaxf(lg[1], lg[2]));
        float ln_d = mg + __logf(__expf(lg[0] - mg) + __expf(lg[1] - mg) + __expf(lg[2] - mg));
        if ((float)t + 0.5f < cl) lacc += (ln_n - ln_d);
      }
    }
  }

  __syncthreads();
  if (l < 16) ((float*)(smem + 32768))[w * 16 + l] = lacc;
  __syncthreads();
  if (w == 0 && l < 16) {
    const float* F = (const float*)(smem + 32768);
    float s = 0.f;
#pragma unroll
    for (int ww = 0; ww < 8; ww++) s += F[ww * 16 + l];
    part[rg * 32 + tg * 16 + l] = s;
  }
}

__global__ void reduce_kernel(const float* __restrict__ part, float* __restrict__ out) {
  int i = blockIdx.x * 256 + threadIdx.x;
  if (i < 4096) {
    int rg = i >> 4, row = i & 15;
    const float* p = part + rg * 32 + row;
    out[i] = p[0] + p[16];
  }
}

extern "C" void kernel_launch(void* const* d_in, const int* in_sizes, int n_in,
                              void* d_out, int out_size, void* d_ws, size_t ws_size,
                              hipStream_t stream) {
  const float* z    = (const float*)d_in[0];
  const float* c    = (const float*)d_in[1];
  const float* b    = (const float*)d_in[2];
  const float* m    = (const float*)d_in[3];
  const float* w_ih = (const float*)d_in[4];
  const float* w_hh = (const float*)d_in[5];
  const float* b_ih = (const float*)d_in[6];
  const float* b_hh = (const float*)d_in[7];
  const float* w1   = (const float*)d_in[8];
  const float* b1   = (const float*)d_in[9];
  const float* w2   = (const float*)d_in[10];
  const float* b2   = (const float*)d_in[11];

  char* ws = (char*)d_ws;
  unsigned short* Whh  = (unsigned short*)(ws);
  unsigned short* Wcat = (unsigned short*)(ws + 393216);
  unsigned short* W1h  = (unsigned short*)(ws + 917504);
  unsigned short* W2b  = (unsigned short*)(ws + 1048576);
  float*          CST  = (float*)(ws + 1056768);
  float*          cnt  = (float*)(ws + 17833984);
  float*          cmax = (float*)(ws + 17850368);
  float*          part = (float*)(ws + 17851392);
  char*           hs   = ws + 17916928;

  hipLaunchKernelGGL(prep_kernel, dim3(N_TOT / 256), dim3(256), 0, stream,
                     w_hh, w_ih, w1, w2, Whh, Wcat, W1h, W2b);
  hipLaunchKernelGGL(const_kernel, dim3(256), dim3(512), 0, stream,
                     c, b, m, b_ih, b_hh, b1, Wcat, CST, cnt, cmax);
  hipLaunchKernelGGL(gru_kernel, dim3(256), dim3(512), 0, stream,
                     z, w_ih, b_hh, Whh, CST, cmax, hs);
  hipLaunchKernelGGL(mlp_kernel, dim3(512), dim3(512), 0, stream,
                     z, b2, cnt, cmax, W1h, W2b, CST, hs, part);
  hipLaunchKernelGGL(reduce_kernel, dim3(16), dim3(256), 0, stream,
                     part, (float*)d_out);
}